// Round 2
// baseline (195.248 us; speedup 1.0000x reference)
//
#include <hip/hip_runtime.h>

// GCN forward: out = PReLU( D^-1/2 (A+I) D^-1/2 (x@W) + b )
// Aggregation commutes with the linear map:
//   xa[i,:] = dinv[i] * ( sum_{s->i} dinv[s]*x[s,:] + dinv[i]*x[i,:] )   [N,128] bf16
//   out     = PReLU( xa @ W + b )                                        [N,512] f32
// CSR built on device (deg histogram -> scan -> fill); no atomics in the
// aggregation or GEMM. Workspace ~30 MB. edge_index arrives as int32.

typedef __attribute__((ext_vector_type(8))) short bf16x8_t;
typedef __attribute__((ext_vector_type(4))) float f32x4;

#define N_NODES 100000
#define N_EDGES 500000
#define K_IN    128
#define H_OUT   512

static __device__ __forceinline__ unsigned short f2b(float f) {
    unsigned u = __float_as_uint(f);
    u = (u + 0x7FFFu + ((u >> 16) & 1u)) >> 16;   // RNE
    return (unsigned short)u;
}

__global__ void k_deg(const int* __restrict__ ei, int* __restrict__ deg) {
    int e = blockIdx.x * 256 + threadIdx.x;
    if (e < N_EDGES) atomicAdd(&deg[ei[N_EDGES + e]], 1);
}

__global__ void k_dinv(const int* __restrict__ deg, float* __restrict__ dinv) {
    int i = blockIdx.x * 256 + threadIdx.x;
    if (i < N_NODES) dinv[i] = rsqrtf((float)(deg[i] + 1));   // +1 self loop
}

__global__ void k_scan1(const int* __restrict__ deg, int* __restrict__ rowstart,
                        int* __restrict__ bsum) {
    __shared__ int s[256];
    int i = blockIdx.x * 256 + threadIdx.x;
    int v = (i < N_NODES) ? deg[i] : 0;
    s[threadIdx.x] = v;
    __syncthreads();
    for (int off = 1; off < 256; off <<= 1) {
        int t = (threadIdx.x >= off) ? s[threadIdx.x - off] : 0;
        __syncthreads();
        s[threadIdx.x] += t;
        __syncthreads();
    }
    if (i < N_NODES) rowstart[i] = s[threadIdx.x] - v;   // exclusive within block
    if (threadIdx.x == 255) bsum[blockIdx.x] = s[255];
}

__global__ void k_scan2(int* __restrict__ bsum, int nb) {
    __shared__ int s[512];
    int v = (threadIdx.x < nb) ? bsum[threadIdx.x] : 0;
    s[threadIdx.x] = v;
    __syncthreads();
    for (int off = 1; off < 512; off <<= 1) {
        int t = (threadIdx.x >= off) ? s[threadIdx.x - off] : 0;
        __syncthreads();
        s[threadIdx.x] += t;
        __syncthreads();
    }
    if (threadIdx.x < nb) bsum[threadIdx.x] = s[threadIdx.x] - v;   // exclusive
}

__global__ void k_scan3(int* __restrict__ rowstart, const int* __restrict__ bsum) {
    int i = blockIdx.x * 256 + threadIdx.x;
    if (i < N_NODES) rowstart[i] += bsum[blockIdx.x];
}

__global__ void k_fill(const int* __restrict__ ei, const int* __restrict__ rowstart,
                       int* __restrict__ cursor, int* __restrict__ csr) {
    int e = blockIdx.x * 256 + threadIdx.x;
    if (e < N_EDGES) {
        int s = ei[e];
        int d = ei[N_EDGES + e];
        int pos = atomicAdd(&cursor[d], 1);
        csr[rowstart[d] + pos] = s;
    }
}

__global__ void k_prepW(const float* __restrict__ W, unsigned short* __restrict__ Wt) {
    int i = blockIdx.x * 256 + threadIdx.x;   // i = n*128 + k
    if (i < K_IN * H_OUT) {
        int n = i >> 7, k = i & 127;
        Wt[i] = f2b(W[k * H_OUT + n]);
    }
}

// Aggregation on the 128-dim input: 1 wave per node, 2 features per lane.
__global__ __launch_bounds__(256) void k_agg(const float* __restrict__ x,
                                             const int* __restrict__ csr,
                                             const int* __restrict__ rowstart,
                                             const int* __restrict__ deg,
                                             const float* __restrict__ dinv,
                                             unsigned* __restrict__ xa) {
    int wave = threadIdx.x >> 6, lane = threadIdx.x & 63;
    int node = blockIdx.x * 4 + wave;
    if (node >= N_NODES) return;

    float di = dinv[node];
    const float2* x2 = (const float2*)x;
    float2 xs = x2[(size_t)node * 64 + lane];
    float a0 = di * xs.x, a1 = di * xs.y;   // self: dinv[i]*x[i]

    int start = rowstart[node], cnt = deg[node];
    for (int j = 0; j < cnt; ++j) {
        int s = csr[start + j];
        float ds = dinv[s];
        float2 v = x2[(size_t)s * 64 + lane];
        a0 += ds * v.x;
        a1 += ds * v.y;
    }
    a0 *= di;
    a1 *= di;
    xa[(size_t)node * 64 + lane] = ((unsigned)f2b(a1) << 16) | f2b(a0);
}

// GEMM: out = PReLU(xa @ W + b). 128x128 tile, 4 waves (2x2), each wave 64x64
// via 4x4 mfma 16x16x32 bf16. LDS A[128][128]bf16, Bt[128][128]bf16, both
// XOR-swizzled per 16B chunk: chunk_stored = chunk ^ (row & 7).
__global__ __launch_bounds__(256) void k_gemm(const unsigned short* __restrict__ xa,
                                              const unsigned short* __restrict__ Wt,
                                              const float* __restrict__ bias,
                                              const float* __restrict__ pw,
                                              float* __restrict__ out) {
    __shared__ uint4 sA[2048];   // 32 KB
    __shared__ uint4 sB[2048];   // 32 KB
    const int tid = threadIdx.x;
    const int m0 = blockIdx.y * 128;
    const int n0 = blockIdx.x * 128;

    const uint4* A4 = (const uint4*)xa;
    const uint4* B4 = (const uint4*)Wt;
    #pragma unroll
    for (int r = 0; r < 8; ++r) {
        int i = tid + r * 256;
        int row = i >> 4, c = i & 15;
        int grow = m0 + row;
        uint4 o = (grow < N_NODES) ? A4[(size_t)grow * 16 + c] : make_uint4(0u, 0u, 0u, 0u);
        sA[row * 16 + (c ^ (row & 7))] = o;
    }
    #pragma unroll
    for (int r = 0; r < 8; ++r) {
        int i = tid + r * 256;
        int row = i >> 4, c = i & 15;
        sB[row * 16 + (c ^ (row & 7))] = B4[(size_t)(n0 + row) * 16 + c];
    }
    __syncthreads();

    const int lane = tid & 63, wave = tid >> 6;
    const int wr = wave >> 1, wc = wave & 1;
    const int l16 = lane & 15, lq = lane >> 4;

    f32x4 acc[4][4];
    #pragma unroll
    for (int m = 0; m < 4; ++m)
        #pragma unroll
        for (int n = 0; n < 4; ++n)
            acc[m][n] = (f32x4){0.f, 0.f, 0.f, 0.f};

    #pragma unroll
    for (int kk = 0; kk < 4; ++kk) {
        bf16x8_t av[4], bv[4];
        #pragma unroll
        for (int m = 0; m < 4; ++m) {
            int row = wr * 64 + m * 16 + l16;
            av[m] = __builtin_bit_cast(bf16x8_t, sA[row * 16 + ((kk * 4 + lq) ^ (row & 7))]);
        }
        #pragma unroll
        for (int n = 0; n < 4; ++n) {
            int row = wc * 64 + n * 16 + l16;
            bv[n] = __builtin_bit_cast(bf16x8_t, sB[row * 16 + ((kk * 4 + lq) ^ (row & 7))]);
        }
        #pragma unroll
        for (int m = 0; m < 4; ++m)
            #pragma unroll
            for (int n = 0; n < 4; ++n)
                acc[m][n] = __builtin_amdgcn_mfma_f32_16x16x32_bf16(av[m], bv[n], acc[m][n], 0, 0, 0);
    }

    // C/D layout: col = l16, row = lq*4 + r  (per 16x16 fragment)
    float bn[4], pn[4];
    #pragma unroll
    for (int n = 0; n < 4; ++n) {
        int gn = n0 + wc * 64 + n * 16 + l16;
        bn[n] = bias[gn];
        pn[n] = pw[gn];
    }
    #pragma unroll
    for (int m = 0; m < 4; ++m) {
        #pragma unroll
        for (int r = 0; r < 4; ++r) {
            int gm = m0 + wr * 64 + m * 16 + lq * 4 + r;
            if (gm < N_NODES) {
                #pragma unroll
                for (int n = 0; n < 4; ++n) {
                    int gn = n0 + wc * 64 + n * 16 + l16;
                    float t = acc[m][n][r] + bn[n];
                    out[(size_t)gm * H_OUT + gn] = t >= 0.f ? t : pn[n] * t;
                }
            }
        }
    }
}

extern "C" void kernel_launch(void* const* d_in, const int* in_sizes, int n_in,
                              void* d_out, int out_size, void* d_ws, size_t ws_size,
                              hipStream_t stream) {
    const float* x    = (const float*)d_in[0];
    const int*   ei   = (const int*)d_in[1];     // int32 per harness convention
    const float* W    = (const float*)d_in[2];
    const float* bias = (const float*)d_in[3];
    const float* pw   = (const float*)d_in[4];
    float* out = (float*)d_out;

    char* ws = (char*)d_ws;
    size_t off = 0;
    auto alloc = [&](size_t bytes) -> void* {
        void* p = ws + off;
        off += (bytes + 255) & ~(size_t)255;
        return p;
    };
    unsigned*       xa = (unsigned*)alloc((size_t)N_NODES * K_IN * 2);       // 25.6 MB (bf16)
    unsigned short* Wt = (unsigned short*)alloc((size_t)K_IN * H_OUT * 2);   // 131 KB
    int*   deg      = (int*)alloc((size_t)N_NODES * 4);
    float* dinv     = (float*)alloc((size_t)N_NODES * 4);
    int*   rowstart = (int*)alloc((size_t)N_NODES * 4);
    int*   cursor   = (int*)alloc((size_t)N_NODES * 4);
    int*   csr      = (int*)alloc((size_t)N_EDGES * 4);
    int*   bsum     = (int*)alloc(512 * 4);
    (void)ws_size; (void)in_sizes; (void)n_in; (void)out_size;

    hipMemsetAsync(deg, 0, (size_t)N_NODES * 4, stream);
    hipMemsetAsync(cursor, 0, (size_t)N_NODES * 4, stream);

    const int nb = (N_NODES + 255) / 256;   // 391
    const int ne = (N_EDGES + 255) / 256;   // 1954
    k_deg  <<<ne, 256, 0, stream>>>(ei, deg);
    k_dinv <<<nb, 256, 0, stream>>>(deg, dinv);
    k_scan1<<<nb, 256, 0, stream>>>(deg, rowstart, bsum);
    k_scan2<<<1, 512, 0, stream>>>(bsum, nb);
    k_scan3<<<nb, 256, 0, stream>>>(rowstart, bsum);
    k_fill <<<ne, 256, 0, stream>>>(ei, rowstart, cursor, csr);
    k_prepW<<<(K_IN * H_OUT + 255) / 256, 256, 0, stream>>>(W, Wt);
    k_agg  <<<(N_NODES + 3) / 4, 256, 0, stream>>>(x, csr, rowstart, deg, dinv, (unsigned*)xa);
    dim3 gg(H_OUT / 128, (N_NODES + 127) / 128);   // (4, 782)
    k_gemm <<<gg, 256, 0, stream>>>((const unsigned short*)xa, Wt, bias, pw, out);
}